// Round 15
// baseline (94.875 us; speedup 1.0000x reference)
//
#include <hip/hip_runtime.h>

// Problem constants: B=8, C=256, H=W=32, NH=8, DK=160, DV=64, DKH=20, DVH=8
constexpr float QSCALE = 0.22360679774997896f; // 1/sqrt(20)
constexpr float LOG2E  = 1.4426950408889634f;

typedef __attribute__((ext_vector_type(8))) short bf16x8;
typedef __attribute__((ext_vector_type(4))) float f32x4;

__device__ __forceinline__ unsigned short f2bf(float f) {
    unsigned u = __float_as_uint(f);
    u = (u + 0x7FFFu + ((u >> 16) & 1u)) >> 16;   // RNE
    return (unsigned short)u;
}

__device__ __forceinline__ unsigned cvt_pk_bf16(float lo, float hi) {
    unsigned r;
    asm("v_cvt_pk_bf16_f32 %0, %1, %2" : "=v"(r) : "v"(lo), "v"(hi));
    return r;
}

// flat (within k- or q-region, per-b) -> head n, row i, dim d (reference reshape)
__device__ __forceinline__ void qk_decomp(unsigned flat, int& n, int& i, int& d) {
    n = flat / 20480u;
    unsigned r = flat - (unsigned)n * 20480u;
    i = r / 20u;
    d = r - (unsigned)i * 20u;
}

// ---- all input packs + attn-buffer pad init, one launch (range-dispatched) -------
__global__ __launch_bounds__(256) void pack_inputs_kernel(
    const float* __restrict__ X, const float* __restrict__ Wconv,
    const float* __restrict__ Wkqv, const float* __restrict__ Wattn,
    unsigned short* __restrict__ Xt2, unsigned short* __restrict__ Xq,
    unsigned short* __restrict__ Wp, unsigned short* __restrict__ Wq,
    unsigned short* __restrict__ Kb, unsigned short* __restrict__ Qb,
    unsigned short* __restrict__ VtF, unsigned short* __restrict__ Wa)
{
    int t = blockIdx.x * 256 + threadIdx.x;        // 3214*256 = 822784
    if (t < 295936) {
        int b = t / 36992, rem = t - b * 36992;
        int chunk = rem / 4624; int rem2 = rem - chunk * 4624;
        int kc = rem2 / 1156;   int spad = rem2 - kc * 1156;
        int yp = spad / 34, xp = spad - yp * 34;
        bf16x8 v = {};
        if (yp >= 1 && yp <= 32 && xp >= 1 && xp <= 32) {
            const float* src = X + (size_t)b * 262144
                                 + (size_t)(chunk * 32 + kc * 8) * 1024
                                 + (yp - 1) * 32 + (xp - 1);
            #pragma unroll
            for (int j = 0; j < 8; ++j) v[j] = (short)f2bf(src[(size_t)j * 1024]);
        }
        *(bf16x8*)&Xt2[(((size_t)b * 8 + chunk) * 1156 + spad) * 32 + kc * 8] = v;
    } else if (t < 558080) {
        int t2 = t - 295936;                       // 262144
        int lane = t2 & 63;
        int chunk = (t2 >> 6) & 7;
        int g16 = (t2 >> 9) & 63;
        int b = t2 >> 15;
        int sp = g16 * 16 + (lane & 15);
        const float* src = X + (size_t)b * 262144
                             + (size_t)(chunk * 32 + (lane >> 4) * 8) * 1024 + sp;
        bf16x8 v;
        #pragma unroll
        for (int j = 0; j < 8; ++j) v[j] = (short)f2bf(src[(size_t)j * 1024]);
        *(bf16x8*)&Xq[(size_t)t2 * 8] = v;
    } else if (t < 613376) {
        int t2 = t - 558080;                       // 55296
        int l = t2 & 63;
        int rb = (t2 >> 6) & 3;
        int ks = (t2 >> 8) % 72;
        int ot = t2 / 18432;
        int oc = ot * 64 + rb * 16 + (l & 15);
        int kbase = ks * 32 + (l >> 4) * 8;
        bf16x8 v;
        #pragma unroll
        for (int j = 0; j < 8; ++j) {
            int kp = kbase + j;
            int r = kp >> 8, c = kp & 255;         // k' = r*256 + c
            v[j] = (short)f2bf(Wconv[((size_t)oc * 256 + c) * 9 + r]);
        }
        *(bf16x8*)&Wp[(size_t)t2 * 8] = v;
    } else if (t < 625664) {
        int t2 = t - 613376;                       // 12288
        int l = t2 & 63;
        int rb = (t2 >> 6) & 3;
        int ks = (t2 >> 8) & 7;
        int ot = t2 / 2048;
        int oc = ot * 64 + rb * 16 + (l & 15);
        float sc = (oc >= 160 && oc < 320) ? QSCALE : 1.0f;
        int kbase = ks * 32 + (l >> 4) * 8;
        bf16x8 v;
        #pragma unroll
        for (int j = 0; j < 8; ++j)
            v[j] = (short)f2bf(Wkqv[(size_t)oc * 256 + kbase + j] * sc);
        *(bf16x8*)&Wq[(size_t)t2 * 8] = v;
    } else if (t < 691200) {
        int row = t - 625664;                      // 65536: Kb pad d=20..31 -> 0
        bf16x8 z = {};
        *(uint2*)&Kb[(size_t)row * 32 + 20] = make_uint2(0u, 0u);
        *(bf16x8*)&Kb[(size_t)row * 32 + 24] = z;
    } else if (t < 756736) {
        int row = t - 691200;                      // 65536: Qb pad
        bf16x8 z = {};
        *(uint2*)&Qb[(size_t)row * 32 + 20] = make_uint2(0u, 0u);
        *(bf16x8*)&Qb[(size_t)row * 32 + 24] = z;
    } else if (t < 822272) {
        // VtF pad rows 8..15 (fragment order): row 8 = ones (lsum), 9..15 = 0
        int t2 = t - 756736;                       // 65536
        int bn = t2 >> 10;
        int G = (t2 >> 5) & 31;                    // 32-key group
        int r8 = (t2 >> 2) & 7;                    // row - 8
        int ksub = t2 & 3;
        unsigned short fill = (r8 == 0) ? 0x3F80 : 0;
        bf16x8 v = {short(fill), short(fill), short(fill), short(fill),
                    short(fill), short(fill), short(fill), short(fill)};
        *(bf16x8*)&VtF[(((size_t)bn * 32 + G) * 64 + (8 + r8) + ksub * 16) * 8] = v;
    } else {
        // attn_w (64x64 1x1) -> A-fragment order Wa[kchunk(2)][rowblk(4)][lane][8]
        int t2 = t - 822272;                       // 512
        int l = t2 & 63;
        int rb = (t2 >> 6) & 3;
        int kchunk = t2 >> 8;                      // 0..1
        int oc = rb * 16 + (l & 15);
        int kbase = kchunk * 32 + (l >> 4) * 8;
        bf16x8 v;
        #pragma unroll
        for (int j = 0; j < 8; ++j)
            v[j] = (short)f2bf(Wattn[(size_t)oc * 64 + kbase + j]);
        *(bf16x8*)&Wa[(size_t)t2 * 8] = v;
    }
}

// ---- fused GEMMs, 512-thread blocks.
// ty 0..2: conv3x3, in-block split-K: 8 waves = (kh, wr, wc); kh halves the
// K-chunks, merged via one LDS exchange + barrier. Direct coalesced B loads.
// ty 3..8: kqv, 8 waves = (wr, wc 0..3), LDS-free, barrier-free. -----------------
__global__ __launch_bounds__(512) void mfma_gemms_kernel(
    const unsigned short* __restrict__ Wp, const unsigned short* __restrict__ Wq,
    const unsigned short* __restrict__ Xt2, const unsigned short* __restrict__ Xq,
    const float* __restrict__ cbias, const float* __restrict__ qbias,
    float* __restrict__ out, float* __restrict__ qf32,
    unsigned short* __restrict__ Kb, unsigned short* __restrict__ Qb,
    unsigned short* __restrict__ VtF)
{
    const int b  = blockIdx.z;
    const int ty = blockIdx.y;                    // 0..8
    const int s0 = blockIdx.x * 64;
    const int tid = threadIdx.x;
    const int lane = tid & 63, w = tid >> 6;      // w 0..7
    const int kc = lane >> 4, ln = lane & 15;

    __shared__ float comb[4][64][17];             // kh=1 partials (17.4 KB)

    f32x4 acc00 = {}, acc01 = {}, acc10 = {}, acc11 = {};

    if (ty < 3) {
        // ---------------- conv path: split-K across kh ----------------
        const int kh = w >> 2, wr = (w >> 1) & 1, wc = w & 1;
        const int wq = wr * 2 + wc;
        const int Y = blockIdx.x * 2;
        const size_t aoff0 = ((size_t)(ty * 288 + wr * 2) * 64 + lane) * 8;
        const size_t aoff1 = aoff0 + 512;
        const int spad0 = (Y + wc + 1) * 34 + 1 + ln;
        const unsigned short* xb = Xt2 + (size_t)b * 8 * 36992;

        #pragma unroll 1
        for (int cc2 = 0; cc2 < 4; ++cc2) {
            const int cc = kh * 4 + cc2;
            bf16x8 A0[9], A1[9];
            #pragma unroll
            for (int r = 0; r < 9; ++r) {
                A0[r] = *(const bf16x8*)&Wp[aoff0 + (size_t)(r * 8 + cc) * 2048];
                A1[r] = *(const bf16x8*)&Wp[aoff1 + (size_t)(r * 8 + cc) * 2048];
            }
            const unsigned short* xc = xb + (size_t)cc * 36992 + kc * 8;
            #pragma unroll
            for (int r = 0; r < 9; ++r) {
                const int off = (r / 3 - 1) * 34 + (r % 3 - 1);
                const unsigned short* bp = xc + (size_t)(spad0 + off) * 32;
                bf16x8 b0 = *(const bf16x8*)bp;
                bf16x8 b1 = *(const bf16x8*)(bp + 512);
                acc00 = __builtin_amdgcn_mfma_f32_16x16x32_bf16(A0[r], b0, acc00, 0, 0, 0);
                acc01 = __builtin_amdgcn_mfma_f32_16x16x32_bf16(A0[r], b1, acc01, 0, 0, 0);
                acc10 = __builtin_amdgcn_mfma_f32_16x16x32_bf16(A1[r], b0, acc10, 0, 0, 0);
                acc11 = __builtin_amdgcn_mfma_f32_16x16x32_bf16(A1[r], b1, acc11, 0, 0, 0);
            }
        }

        if (kh == 1) {
            float* c0 = &comb[wq][lane][0];
            #pragma unroll
            for (int r = 0; r < 4; ++r) {
                c0[r]      = acc00[r];
                c0[4 + r]  = acc01[r];
                c0[8 + r]  = acc10[r];
                c0[12 + r] = acc11[r];
            }
        }
        __syncthreads();
        if (kh == 0) {
            const float* c0 = &comb[wq][lane][0];
            #pragma unroll
            for (int r = 0; r < 4; ++r) {
                acc00[r] += c0[r];
                acc01[r] += c0[4 + r];
                acc10[r] += c0[8 + r];
                acc11[r] += c0[12 + r];
            }
            const int ocb = ty * 64 + wr * 32;
            const int scol = s0 + wc * 32 + ln;
            float* ob = out + (size_t)b * 262144;
            #pragma unroll
            for (int r = 0; r < 4; ++r) {
                int oc0 = ocb + kc * 4 + r;
                float b0v = cbias[oc0];
                ob[(size_t)oc0 * 1024 + scol]      = acc00[r] + b0v;
                ob[(size_t)oc0 * 1024 + scol + 16] = acc01[r] + b0v;
                int oc1 = oc0 + 16;
                float b1v = cbias[oc1];
                ob[(size_t)oc1 * 1024 + scol]      = acc10[r] + b1v;
                ob[(size_t)oc1 * 1024 + scol + 16] = acc11[r] + b1v;
            }
        }
    } else {
        // ---------------- kqv path: 8 waves = (wr, wc 0..3) ----------------
        const int ot = ty - 3;                    // 0..5
        const int wr = w >> 2, wc = w & 3;
        const size_t aoff0 = ((size_t)(ot * 32 + wr * 2) * 64 + lane) * 8;
        const size_t aoff1 = aoff0 + 512;
        const int g0 = blockIdx.x * 4 + wc;       // 16-sp group 0..63
        const size_t xb0 = (((size_t)b * 64 + g0) * 8) * 512 + lane * 8;

        #pragma unroll
        for (int cc = 0; cc < 8; ++cc) {
            bf16x8 a0 = *(const bf16x8*)&Wq[aoff0 + (size_t)cc * 2048];
            bf16x8 a1 = *(const bf16x8*)&Wq[aoff1 + (size_t)cc * 2048];
            bf16x8 b0 = *(const bf16x8*)&Xq[xb0 + (size_t)cc * 512];
            acc00 = __builtin_amdgcn_mfma_f32_16x16x32_bf16(a0, b0, acc00, 0, 0, 0);
            acc10 = __builtin_amdgcn_mfma_f32_16x16x32_bf16(a1, b0, acc10, 0, 0, 0);
        }

        const int ocb = ot * 64 + wr * 32;
        const int scol = s0 + wc * 16 + ln;
        const int b8 = b * 8;
        #pragma unroll
        for (int r = 0; r < 4; ++r) {
            #pragma unroll
            for (int e = 0; e < 2; ++e) {         // oc halves within wr-half
                int oc  = ocb + e * 16 + kc * 4 + r;
                float val = e ? acc10[r] : acc00[r];
                int col = scol;
                if (oc < 160) {                   // K
                    float v = val + qbias[oc];
                    int n, i, d; qk_decomp((unsigned)oc * 1024u + col, n, i, d);
                    Kb[(((size_t)(b8 + n) * 1024 + i) << 5) + d] = f2bf(v);
                } else if (oc < 320) {            // Q (QSCALE folded; LOG2E for Qb)
                    float v = val + qbias[oc] * QSCALE;
                    unsigned flat = (unsigned)(oc - 160) * 1024u + col;
                    qf32[(size_t)b * 163840 + flat] = v;
                    int n, i, d; qk_decomp(flat, n, i, d);
                    Qb[(((size_t)(b8 + n) * 1024 + i) << 5) + d] = f2bf(v * LOG2E);
                } else {                          // V -> VtF fragment order
                    float v = val + qbias[oc];
                    unsigned flat = (unsigned)(oc - 320) * 1024u + col;
                    int n = flat >> 13, i = (flat >> 3) & 1023, dd = flat & 7;
                    int G = i >> 5, k0 = i & 31;
                    VtF[((((size_t)(b8 + n) * 32 + G) * 64) + dd + ((k0 >> 3) << 4)) * 8
                        + (k0 & 7)] = f2bf(v);
                }
            }
        }
    }
}

// ---- rel logits with in-kernel head-sum (reads q-only f32) -----------------------
__global__ __launch_bounds__(256) void rel_kernel(
    const float* __restrict__ qf32,
    const float* __restrict__ rel_h, const float* __restrict__ rel_w,
    float* __restrict__ Rh, float* __restrict__ Rw)
{
    const int blk = blockIdx.x;                   // 512
    const int b = blk >> 6, st = blk & 63;
    const int s0 = st * 16;
    const int tid = threadIdx.x;
    __shared__ float rhS[63][21];
    __shared__ float rwS[63][21];
    __shared__ float qs[16][20];

    for (int i = tid; i < 1260; i += 256) {
        int mm = i / 20, d = i - mm * 20;
        rhS[mm][d] = rel_h[i];
        rwS[mm][d] = rel_w[i];
    }
    for (int e = tid; e < 320; e += 256) {
        int s = e / 20, d = e - s * 20;
        const float* qb = qf32 + (size_t)b * 163840 + (s0 + s) * 20 + d;
        float acc = 0.0f;
        #pragma unroll
        for (int n = 0; n < 8; ++n) acc += qb[(size_t)n * 20480];
        qs[s][d] = acc;
    }
    __syncthreads();

    for (int p = tid; p < 1008; p += 256) {
        int s = p / 63, mm = p - s * 63;
        float sh = 0.0f, sw = 0.0f;
        #pragma unroll
        for (int d = 0; d < 20; ++d) {
            float qv = qs[s][d];
            sh += qv * rhS[mm][d];
            sw += qv * rwS[mm][d];
        }
        int sg = s0 + s;
        int y = sg >> 5, x = sg & 31;
        Rw[(size_t)b * 64512 + sg * 63 + mm] = sw * LOG2E;
        Rh[(size_t)b * 64512 + (x * 32 + y) * 63 + mm] = sh * LOG2E;
    }
}

// ---------------- MFMA flash attention, fixed-max (M=0), full-K per wave ----------
__global__ __launch_bounds__(256, 4) void attn_mfma_kernel(
    const unsigned short* __restrict__ Qb, const unsigned short* __restrict__ Kb,
    const unsigned short* __restrict__ VtF, const float* __restrict__ Rh,
    const float* __restrict__ Rw, float* __restrict__ attnout)
{
    const int bn = blockIdx.y;                    // b*8+n
    const int b = bn >> 3;
    const int i0 = blockIdx.x * 64;
    const int tid = threadIdx.x;
    const int lane = tid & 63, w = tid >> 6;

    __shared__ float RhS[64][33];
    __shared__ float RwS[64][33];
    __shared__ unsigned short Pl[4][16][72];      // per-wave P^T tile
    {
        int q = tid & 63, seg = tid >> 6;
        int i = i0 + q, y1 = i >> 5, x1 = i & 31;
        const float* rh = Rh + (size_t)b * 64512 + (x1 * 32 + y1) * 63 + 31 - y1 + seg * 8;
        const float* rw = Rw + (size_t)b * 64512 + i * 63 + 31 - x1 + seg * 8;
        #pragma unroll
        for (int j = 0; j < 8; ++j) {
            RhS[q][seg * 8 + j] = rh[j];
            RwS[q][seg * 8 + j] = rw[j];
        }
    }
    __syncthreads();

    const int ql = lane & 15, g = lane >> 4;
    const int qw = i0 + w * 16;

    bf16x8 qf = *(const bf16x8*)&Qb[((size_t)bn * 1024 + qw + ql) * 32 + g * 8];
    const unsigned short* kp = Kb + ((size_t)bn * 1024 + ql) * 32 + g * 8;
    const unsigned short* vp = VtF + (size_t)bn * 32 * 512 + lane * 8;

    const float* rhrow = &RhS[w * 16 + ql][0];
    float rwA[4], rwB[4];
    #pragma unroll
    for (int r = 0; r < 4; ++r) {
        rwA[r] = RwS[w * 16 + ql][4 * g + r];
        rwB[r] = RwS[w * 16 + ql][16 + 4 * g + r];
    }

    f32x4 oaccT = {};                              // O^T rows g*4+r (row 8 = lsum)

    bf16x8 c0 = *(const bf16x8*)&kp[0 * 512];
    bf16x8 c1 = *(const bf16x8*)&kp[1 * 512];
    bf16x8 c2 = *(const bf16x8*)&kp[2 * 512];
    bf16x8 c3 = *(const bf16x8*)&kp[3 * 512];

    #pragma unroll 2
    for (int kt = 0; kt < 16; ++kt) {
        __builtin_amdgcn_s_setprio(1);
        f32x4 s0 = {}, s1 = {}, s2 = {}, s3 = {};
        s0 = __builtin_amdgcn_mfma_f32_16x16x32_bf16(c0, qf, s0, 0, 0, 0);
        s1 = __builtin_amdgcn_mfma_f32_16x16x32_bf16(c1, qf, s1, 0, 0, 0);
        s2 = __builtin_amdgcn_mfma_f32_16x16x32_bf16(c2, qf, s2, 0, 0, 0);
        s3 = __builtin_amdgcn_mfma_f32_16x16x32_bf16(c3, qf, s3, 0, 0, 0);
        __builtin_amdgcn_s_setprio(0);

        if (kt < 15) {                             // prefetch next K tile
            kp += 2048;
            c0 = *(const bf16x8*)&kp[0 * 512];
            c1 = *(const bf16x8*)&kp[1 * 512];
            c2 = *(const bf16x8*)&kp[2 * 512];
            c3 = *(const bf16x8*)&kp[3 * 512];
        }

        float rh0 = rhrow[2 * kt];
        float rh1 = rhrow[2 * kt + 1];

        // P = exp2(logit) directly (fixed max = 0) -> bf16 -> per-wave LDS
        float p00 = exp2f(s0[0] + rh0 + rwA[0]), p01 = exp2f(s0[1] + rh0 + rwA[1]);
        float p02 = exp2f(s0[2] + rh0 + rwA[2]), p03 = exp2f(s0[3] + rh0 + rwA[3]);
        float p10 = exp2f(s1[0] + rh0 + rwB[0]), p11 = exp2f(s1[1] + rh0 + rwB[1]);
        float p12 = exp2f(s1[2] + rh0 + rwB[2]), p13 = exp2f(s1[3] + rh0 + rwB[3]);
        float p20 = exp2f(s2[0] + rh1 + rwA[0]), p21 = exp2f(s2[1] + rh1 + rwA[1]);
        float p22 = exp2f(s2[2] + rh1 + rwA[2]), p23 = exp2f(s2[3] + rh1 + rwA[3]);
        float p30 = exp2f(s3[0] + rh1 + rwB[0]), p31 = exp2f(s3[1] + rh1 + rwB[1]);
        float p32 = exp2f(s3[2] + rh1 + rwB[2]), p33 = exp2f(s3[3] + rh1 + rwB[3]);

        const int key = 4 * g;
        *(unsigned*)&Pl[w][ql][key]      = cvt_pk_bf16(p00, p01);
        *(unsigned*)&Pl[w][ql][key + 2]  = cvt_pk_bf16(p02, p03);
        *(unsigned*)&Pl[w][ql][key + 16] = cvt_pk_bf16(p10, p11);
        *(unsigned*)&Pl[w][ql][key + 18] = cvt_pk_bf16(p12, p13);
        *(unsigned*)&Pl[w][ql][key + 32] = cvt_pk_bf16(p20, p21);
        *(unsigned*)&Pl[w][ql][key + 34] = cvt_pk_bf16(p22, p23);
        *(unsigned*)&Pl[w][ql][key + 48] = cvt_pk_bf16(p30, p31);
        *(unsigned*)&Pl[w][ql][key + 50] = cvt_pk_bf16(p32, p33);

        // O^T += V^T(keys) @ P^T  (VtF fragment-order: contiguous 1KB per frag)
        #pragma unroll
        for (int half = 0; half < 2; ++half) {
            bf16x8 vfr = *(const bf16x8*)&vp[(size_t)(kt * 2 + half) * 512];
            bf16x8 pfr = *(const bf16x8*)&Pl[w][ql][half * 32 + g * 8];
            __builtin_amdgcn_s_setprio(1);
            oaccT = __builtin_amdgcn_mfma_f32_16x16x32_bf16(vfr, pfr, oaccT, 0, 0, 0);
            __builtin_amdgcn_s_setprio(0);
        }
    }

    float lsum = __shfl(oaccT[0], 32 + ql, 64);    // row 8 lives in lane g=2, reg 0
    float inv = 1.0f / lsum;
    if (g < 2) {
        float4 o = {oaccT[0] * inv, oaccT[1] * inv, oaccT[2] * inv, oaccT[3] * inv};
        *(float4*)&attnout[((size_t)bn * 1024 + qw + ql) * 8 + g * 4] = o;
    }
}

// ---- attn 1x1 conv as MFMA: out[192+oc][s] = W[oc][c] @ attn_flat[c][s] per b ----
// B-frag: channel c lives at FLAT offset c*1024+s of the attn buffer (reference
// reshape is a flat reinterpretation) -> 8 stride-1024 f32 loads per lane.
__global__ __launch_bounds__(256) void attn_out_mfma_kernel(
    const unsigned short* __restrict__ Wa, const float* __restrict__ attn,
    const float* __restrict__ bias, float* __restrict__ out)
{
    const int b = blockIdx.y;
    const int tid = threadIdx.x;
    const int w = tid >> 6, lane = tid & 63;
    const int sg = blockIdx.x * 4 + w;            // 16-sp group, 0..63
    const int kc = lane >> 4, ln = lane & 15;
    const int s = sg * 16 + ln;

    const float* ab = attn + (size_t)b * 65536 + s;

    f32x4 acc0 = {}, acc1 = {}, acc2 = {}, acc3 = {};
    #pragma unroll
    for (int kchunk = 0; kchunk < 2; ++kchunk) {
        const int c0 = kchunk * 32 + kc * 8;
        const float* cp = ab + (size_t)c0 * 1024;
        bf16x8 bf;
        #pragma unroll
        for (int j = 0; j < 8; j += 2) {
            unsigned u = cvt_pk_bf16(cp[(size_t)j * 1024], cp[(size_t)(j + 1) * 1024]);
            bf[j]     = (short)u;
            bf[j + 1] = (short)(u >> 16);
        }

        const unsigned short* wp = Wa + (size_t)kchunk * 2048;
        bf16x8 a0 = *(const bf16x8*)&wp[(size_t)(0 * 64 + lane) * 8];
        bf16x8 a1 = *(const bf16x8*)&wp[(size_t)(1 * 64 + lane) * 8];
        bf16x8 a2 = *(const bf16x8*)&wp[(size_t)(2 * 64 + lane) * 8];
        bf16x8 a3 = *(const bf16x8*)&wp[(size_t)(3 * 64 + lane) * 8];
        acc0 = __builtin_amdgcn_mfma_f32_16x16x32_bf16(a0, bf, acc0, 0, 0, 0);
        acc1 = __builtin_amdgcn_mfma_f32_16x16x32_bf16(a1, bf, acc1, 0, 0, 0);
        acc2 = __builtin_amdgcn_mfma_f32_16x16x32_bf16(a2, bf, acc2, 0, 0, 0);
        acc3 = __builtin_amdgcn_mfma_f32_16x16x32_bf16(a3, bf, acc3, 0, 0, 0);
    }

    float* ob = out + ((size_t)b * 256 + 192) * 1024 + s;
    #pragma unroll
    for (int r = 0; r < 4; ++r) {
        int oc0 = 0 * 16 + kc * 4 + r;
        int oc1 = 1 * 16 + kc * 4 + r;
        int oc2 = 2 * 16 + kc * 4 + r;
        int oc3 = 3 * 16 + kc * 4 + r;
        ob[(size_t)oc0 * 1024] = acc0[r] + bias[oc0];
        ob[(size_t)oc1 * 1024] = acc1[r] + bias[oc1];
        ob[(size_t)oc2 * 1024] = acc2[r] + bias[oc2];
        ob[(size_t)oc3 * 1024] = acc3[r] + bias[oc3];
    }
}

extern "C" void kernel_launch(void* const* d_in, const int* in_sizes, int n_in,
                              void* d_out, int out_size, void* d_ws, size_t ws_size,
                              hipStream_t stream)
{
    const float* x          = (const float*)d_in[0];
    const float* kqv_w      = (const float*)d_in[1];
    const float* kqv_b      = (const float*)d_in[2];
    const float* conv_out_w = (const float*)d_in[3];
    const float* conv_out_b = (const float*)d_in[4];
    const float* attn_w     = (const float*)d_in[5];
    const float* attn_b     = (const float*)d_in[6];
    const float* rel_h      = (const float*)d_in[7];
    const float* rel_w      = (const float*)d_in[8];
    float* out = (float*)d_out;
    float* ws  = (float*)d_ws;

    // Disjoint layout (f32 offsets); ~32 MB total.
    float* ws_qf32 = ws;                                   // 1,310,720
    float* ws_rw   = ws + 1310720;                         //   516,096
    float* ws_rh   = ws + 1826816;                         //   516,096
    float* ws_attn = ws + 2342912;                         //   524,288
    unsigned short* Qb  = (unsigned short*)(ws + 2867200); // 2,097,152 u16
    unsigned short* Kb  = (unsigned short*)(ws + 3915776); // 2,097,152 u16
    unsigned short* VtF = (unsigned short*)(ws + 4964352); // 1,048,576 u16
    unsigned short* Xt2 = (unsigned short*)(ws + 5488640); // 2,367,488 u16
    unsigned short* Xq  = (unsigned short*)(ws + 6672384); // 2,097,152 u16
    unsigned short* Wp  = (unsigned short*)(ws + 7720960); //   442,368 u16
    unsigned short* Wq  = (unsigned short*)(ws + 7942144); //    98,304 u16
    unsigned short* Wa  = (unsigned short*)(ws + 7991296); //     4,096 u16

    pack_inputs_kernel<<<3214, 256, 0, stream>>>(
        x, conv_out_w, kqv_w, attn_w, Xt2, Xq, Wp, Wq, Kb, Qb, VtF, Wa);
    mfma_gemms_kernel<<<dim3(16, 9, 8), 512, 0, stream>>>(
        Wp, Wq, Xt2, Xq, conv_out_b, kqv_b, out, ws_qf32, Kb, Qb, VtF);
    rel_kernel<<<512, 256, 0, stream>>>(ws_qf32, rel_h, rel_w, ws_rh, ws_rw);
    attn_mfma_kernel<<<dim3(16, 64), 256, 0, stream>>>(
        Qb, Kb, VtF, ws_rh, ws_rw, ws_attn);
    attn_out_mfma_kernel<<<dim3(16, 8), 256, 0, stream>>>(
        Wa, ws_attn, attn_b, out);
}

// Round 16
// 83.726 us; speedup vs baseline: 1.1332x; 1.1332x over previous
//
#include <hip/hip_runtime.h>

// Problem constants: B=8, C=256, H=W=32, NH=8, DK=160, DV=64, DKH=20, DVH=8
constexpr float QSCALE = 0.22360679774997896f; // 1/sqrt(20)
constexpr float LOG2E  = 1.4426950408889634f;

typedef __attribute__((ext_vector_type(8))) short bf16x8;
typedef __attribute__((ext_vector_type(4))) float f32x4;

__device__ __forceinline__ unsigned short f2bf(float f) {
    unsigned u = __float_as_uint(f);
    u = (u + 0x7FFFu + ((u >> 16) & 1u)) >> 16;   // RNE
    return (unsigned short)u;
}

__device__ __forceinline__ unsigned cvt_pk_bf16(float lo, float hi) {
    unsigned r;
    asm("v_cvt_pk_bf16_f32 %0, %1, %2" : "=v"(r) : "v"(lo), "v"(hi));
    return r;
}

// flat (within k- or q-region, per-b) -> head n, row i, dim d (reference reshape)
__device__ __forceinline__ void qk_decomp(unsigned flat, int& n, int& i, int& d) {
    n = flat / 20480u;
    unsigned r = flat - (unsigned)n * 20480u;
    i = r / 20u;
    d = r - (unsigned)i * 20u;
}

// ---- all input packs + attn-buffer pad init, one launch (range-dispatched) -------
__global__ __launch_bounds__(256) void pack_inputs_kernel(
    const float* __restrict__ X, const float* __restrict__ Wconv,
    const float* __restrict__ Wkqv, const float* __restrict__ Wattn,
    unsigned short* __restrict__ Xt2, unsigned short* __restrict__ Xq,
    unsigned short* __restrict__ Wp, unsigned short* __restrict__ Wq,
    unsigned short* __restrict__ Kb, unsigned short* __restrict__ Qb,
    unsigned short* __restrict__ VtF, unsigned short* __restrict__ Wa)
{
    int t = blockIdx.x * 256 + threadIdx.x;        // 3214*256 = 822784
    if (t < 295936) {
        int b = t / 36992, rem = t - b * 36992;
        int chunk = rem / 4624; int rem2 = rem - chunk * 4624;
        int kc = rem2 / 1156;   int spad = rem2 - kc * 1156;
        int yp = spad / 34, xp = spad - yp * 34;
        bf16x8 v = {};
        if (yp >= 1 && yp <= 32 && xp >= 1 && xp <= 32) {
            const float* src = X + (size_t)b * 262144
                                 + (size_t)(chunk * 32 + kc * 8) * 1024
                                 + (yp - 1) * 32 + (xp - 1);
            #pragma unroll
            for (int j = 0; j < 8; ++j) v[j] = (short)f2bf(src[(size_t)j * 1024]);
        }
        *(bf16x8*)&Xt2[(((size_t)b * 8 + chunk) * 1156 + spad) * 32 + kc * 8] = v;
    } else if (t < 558080) {
        int t2 = t - 295936;                       // 262144
        int lane = t2 & 63;
        int chunk = (t2 >> 6) & 7;
        int g16 = (t2 >> 9) & 63;
        int b = t2 >> 15;
        int sp = g16 * 16 + (lane & 15);
        const float* src = X + (size_t)b * 262144
                             + (size_t)(chunk * 32 + (lane >> 4) * 8) * 1024 + sp;
        bf16x8 v;
        #pragma unroll
        for (int j = 0; j < 8; ++j) v[j] = (short)f2bf(src[(size_t)j * 1024]);
        *(bf16x8*)&Xq[(size_t)t2 * 8] = v;
    } else if (t < 613376) {
        int t2 = t - 558080;                       // 55296
        int l = t2 & 63;
        int rb = (t2 >> 6) & 3;
        int ks = (t2 >> 8) % 72;
        int ot = t2 / 18432;
        int oc = ot * 64 + rb * 16 + (l & 15);
        int kbase = ks * 32 + (l >> 4) * 8;
        bf16x8 v;
        #pragma unroll
        for (int j = 0; j < 8; ++j) {
            int kp = kbase + j;
            int r = kp >> 8, c = kp & 255;         // k' = r*256 + c
            v[j] = (short)f2bf(Wconv[((size_t)oc * 256 + c) * 9 + r]);
        }
        *(bf16x8*)&Wp[(size_t)t2 * 8] = v;
    } else if (t < 625664) {
        int t2 = t - 613376;                       // 12288
        int l = t2 & 63;
        int rb = (t2 >> 6) & 3;
        int ks = (t2 >> 8) & 7;
        int ot = t2 / 2048;
        int oc = ot * 64 + rb * 16 + (l & 15);
        float sc = (oc >= 160 && oc < 320) ? QSCALE : 1.0f;
        int kbase = ks * 32 + (l >> 4) * 8;
        bf16x8 v;
        #pragma unroll
        for (int j = 0; j < 8; ++j)
            v[j] = (short)f2bf(Wkqv[(size_t)oc * 256 + kbase + j] * sc);
        *(bf16x8*)&Wq[(size_t)t2 * 8] = v;
    } else if (t < 691200) {
        int row = t - 625664;                      // 65536: Kb pad d=20..31 -> 0
        bf16x8 z = {};
        *(uint2*)&Kb[(size_t)row * 32 + 20] = make_uint2(0u, 0u);
        *(bf16x8*)&Kb[(size_t)row * 32 + 24] = z;
    } else if (t < 756736) {
        int row = t - 691200;                      // 65536: Qb pad
        bf16x8 z = {};
        *(uint2*)&Qb[(size_t)row * 32 + 20] = make_uint2(0u, 0u);
        *(bf16x8*)&Qb[(size_t)row * 32 + 24] = z;
    } else if (t < 822272) {
        // VtF pad rows 8..15 (fragment order): row 8 = ones (lsum), 9..15 = 0
        int t2 = t - 756736;                       // 65536
        int bn = t2 >> 10;
        int G = (t2 >> 5) & 31;                    // 32-key group
        int r8 = (t2 >> 2) & 7;                    // row - 8
        int ksub = t2 & 3;
        unsigned short fill = (r8 == 0) ? 0x3F80 : 0;
        bf16x8 v = {short(fill), short(fill), short(fill), short(fill),
                    short(fill), short(fill), short(fill), short(fill)};
        *(bf16x8*)&VtF[(((size_t)bn * 32 + G) * 64 + (8 + r8) + ksub * 16) * 8] = v;
    } else {
        // attn_w (64x64 1x1) -> A-fragment order Wa[kchunk(2)][rowblk(4)][lane][8]
        int t2 = t - 822272;                       // 512
        int l = t2 & 63;
        int rb = (t2 >> 6) & 3;
        int kchunk = t2 >> 8;                      // 0..1
        int oc = rb * 16 + (l & 15);
        int kbase = kchunk * 32 + (l >> 4) * 8;
        bf16x8 v;
        #pragma unroll
        for (int j = 0; j < 8; ++j)
            v[j] = (short)f2bf(Wattn[(size_t)oc * 64 + kbase + j]);
        *(bf16x8*)&Wa[(size_t)t2 * 8] = v;
    }
}

// ---- fused GEMMs, LDS-free/barrier-free (R13 structure, measured best).
// ty 0..2: conv3x3 -> out; ty 3..8: kqv -> packed bf16 Kb/Qb/VtF + q-only f32. ----
__global__ __launch_bounds__(256) void mfma_gemms_kernel(
    const unsigned short* __restrict__ Wp, const unsigned short* __restrict__ Wq,
    const unsigned short* __restrict__ Xt2, const unsigned short* __restrict__ Xq,
    const float* __restrict__ cbias, const float* __restrict__ qbias,
    float* __restrict__ out, float* __restrict__ qf32,
    unsigned short* __restrict__ Kb, unsigned short* __restrict__ Qb,
    unsigned short* __restrict__ VtF)
{
    const int b  = blockIdx.z;
    const int ty = blockIdx.y;                    // 0..8
    const int s0 = blockIdx.x * 64;
    const int tid = threadIdx.x;
    const int lane = tid & 63, w = tid >> 6;
    const int wr = w >> 1, wc = w & 1;
    const int kc = lane >> 4, ln = lane & 15;

    f32x4 acc00 = {}, acc01 = {}, acc10 = {}, acc11 = {};
    const int scol = s0 + wc * 32 + ln;

    if (ty < 3) {
        // ---------------- conv path: direct coalesced B loads, no LDS -----------
        const int Y = blockIdx.x * 2;
        const size_t aoff0 = ((size_t)(ty * 288 + wr * 2) * 64 + lane) * 8;
        const size_t aoff1 = aoff0 + 512;
        const int spad0 = (Y + wc + 1) * 34 + 1 + ln;
        const unsigned short* xb = Xt2 + (size_t)b * 8 * 36992;

        #pragma unroll 1
        for (int cc = 0; cc < 8; ++cc) {
            bf16x8 A0[9], A1[9];
            #pragma unroll
            for (int r = 0; r < 9; ++r) {
                A0[r] = *(const bf16x8*)&Wp[aoff0 + (size_t)(r * 8 + cc) * 2048];
                A1[r] = *(const bf16x8*)&Wp[aoff1 + (size_t)(r * 8 + cc) * 2048];
            }
            const unsigned short* xc = xb + (size_t)cc * 36992 + kc * 8;
            #pragma unroll
            for (int r = 0; r < 9; ++r) {
                const int off = (r / 3 - 1) * 34 + (r % 3 - 1);
                const unsigned short* bp = xc + (size_t)(spad0 + off) * 32;
                bf16x8 b0 = *(const bf16x8*)bp;
                bf16x8 b1 = *(const bf16x8*)(bp + 512);
                acc00 = __builtin_amdgcn_mfma_f32_16x16x32_bf16(A0[r], b0, acc00, 0, 0, 0);
                acc01 = __builtin_amdgcn_mfma_f32_16x16x32_bf16(A0[r], b1, acc01, 0, 0, 0);
                acc10 = __builtin_amdgcn_mfma_f32_16x16x32_bf16(A1[r], b0, acc10, 0, 0, 0);
                acc11 = __builtin_amdgcn_mfma_f32_16x16x32_bf16(A1[r], b1, acc11, 0, 0, 0);
            }
        }

        const int ocb = ty * 64 + wr * 32;
        float* ob = out + (size_t)b * 262144;
        #pragma unroll
        for (int r = 0; r < 4; ++r) {
            int oc0 = ocb + kc * 4 + r;
            float b0v = cbias[oc0];
            ob[(size_t)oc0 * 1024 + scol]      = acc00[r] + b0v;
            ob[(size_t)oc0 * 1024 + scol + 16] = acc01[r] + b0v;
            int oc1 = oc0 + 16;
            float b1v = cbias[oc1];
            ob[(size_t)oc1 * 1024 + scol]      = acc10[r] + b1v;
            ob[(size_t)oc1 * 1024 + scol + 16] = acc11[r] + b1v;
        }
    } else {
        // ---------------- kqv path (LDS-free) with packed bf16 epilogue ---------
        const int ot = ty - 3;                    // 0..5
        const size_t aoff0 = ((size_t)(ot * 32 + wr * 2) * 64 + lane) * 8;
        const size_t aoff1 = aoff0 + 512;
        const int g0 = blockIdx.x * 4 + wc * 2;
        const size_t xb0 = (((size_t)b * 64 + g0) * 8) * 512 + lane * 8;
        const size_t xb1 = xb0 + 4096;

        #pragma unroll
        for (int cc = 0; cc < 8; ++cc) {
            bf16x8 a0 = *(const bf16x8*)&Wq[aoff0 + (size_t)cc * 2048];
            bf16x8 a1 = *(const bf16x8*)&Wq[aoff1 + (size_t)cc * 2048];
            bf16x8 b0 = *(const bf16x8*)&Xq[xb0 + (size_t)cc * 512];
            bf16x8 b1 = *(const bf16x8*)&Xq[xb1 + (size_t)cc * 512];
            acc00 = __builtin_amdgcn_mfma_f32_16x16x32_bf16(a0, b0, acc00, 0, 0, 0);
            acc01 = __builtin_amdgcn_mfma_f32_16x16x32_bf16(a0, b1, acc01, 0, 0, 0);
            acc10 = __builtin_amdgcn_mfma_f32_16x16x32_bf16(a1, b0, acc10, 0, 0, 0);
            acc11 = __builtin_amdgcn_mfma_f32_16x16x32_bf16(a1, b1, acc11, 0, 0, 0);
        }

        const int ocb = ot * 64 + wr * 32;
        const int b8 = b * 8;
        #pragma unroll
        for (int r = 0; r < 4; ++r) {
            #pragma unroll
            for (int e = 0; e < 4; ++e) {         // {oc half, col half}
                int oc  = ocb + (e >> 1) * 16 + kc * 4 + r;
                int col = scol + (e & 1) * 16;
                float val = (e == 0) ? acc00[r] : (e == 1) ? acc01[r]
                          : (e == 2) ? acc10[r] : acc11[r];
                if (oc < 160) {                   // K
                    float v = val + qbias[oc];
                    int n, i, d; qk_decomp((unsigned)oc * 1024u + col, n, i, d);
                    Kb[(((size_t)(b8 + n) * 1024 + i) << 5) + d] = f2bf(v);
                } else if (oc < 320) {            // Q (QSCALE folded; LOG2E for Qb)
                    float v = val + qbias[oc] * QSCALE;
                    unsigned flat = (unsigned)(oc - 160) * 1024u + col;
                    qf32[(size_t)b * 163840 + flat] = v;
                    int n, i, d; qk_decomp(flat, n, i, d);
                    Qb[(((size_t)(b8 + n) * 1024 + i) << 5) + d] = f2bf(v * LOG2E);
                } else {                          // V -> VtF fragment order
                    float v = val + qbias[oc];
                    unsigned flat = (unsigned)(oc - 320) * 1024u + col;
                    int n = flat >> 13, i = (flat >> 3) & 1023, dd = flat & 7;
                    int G = i >> 5, k0 = i & 31;
                    VtF[((((size_t)(b8 + n) * 32 + G) * 64) + dd + ((k0 >> 3) << 4)) * 8
                        + (k0 & 7)] = f2bf(v);
                }
            }
        }
    }
}

// ---- rel logits with in-kernel head-sum (reads q-only f32) -----------------------
__global__ __launch_bounds__(256) void rel_kernel(
    const float* __restrict__ qf32,
    const float* __restrict__ rel_h, const float* __restrict__ rel_w,
    float* __restrict__ Rh, float* __restrict__ Rw)
{
    const int blk = blockIdx.x;                   // 512
    const int b = blk >> 6, st = blk & 63;
    const int s0 = st * 16;
    const int tid = threadIdx.x;
    __shared__ float rhS[63][21];
    __shared__ float rwS[63][21];
    __shared__ float qs[16][20];

    for (int i = tid; i < 1260; i += 256) {
        int mm = i / 20, d = i - mm * 20;
        rhS[mm][d] = rel_h[i];
        rwS[mm][d] = rel_w[i];
    }
    for (int e = tid; e < 320; e += 256) {
        int s = e / 20, d = e - s * 20;
        const float* qb = qf32 + (size_t)b * 163840 + (s0 + s) * 20 + d;
        float acc = 0.0f;
        #pragma unroll
        for (int n = 0; n < 8; ++n) acc += qb[(size_t)n * 20480];
        qs[s][d] = acc;
    }
    __syncthreads();

    for (int p = tid; p < 1008; p += 256) {
        int s = p / 63, mm = p - s * 63;
        float sh = 0.0f, sw = 0.0f;
        #pragma unroll
        for (int d = 0; d < 20; ++d) {
            float qv = qs[s][d];
            sh += qv * rhS[mm][d];
            sw += qv * rwS[mm][d];
        }
        int sg = s0 + s;
        int y = sg >> 5, x = sg & 31;
        Rw[(size_t)b * 64512 + sg * 63 + mm] = sw * LOG2E;
        Rh[(size_t)b * 64512 + (x * 32 + y) * 63 + mm] = sh * LOG2E;
    }
}

// ---------------- MFMA flash attention, fixed-max (M=0), full-K per wave ----------
__global__ __launch_bounds__(256, 4) void attn_mfma_kernel(
    const unsigned short* __restrict__ Qb, const unsigned short* __restrict__ Kb,
    const unsigned short* __restrict__ VtF, const float* __restrict__ Rh,
    const float* __restrict__ Rw, float* __restrict__ attnout)
{
    const int bn = blockIdx.y;                    // b*8+n
    const int b = bn >> 3;
    const int i0 = blockIdx.x * 64;
    const int tid = threadIdx.x;
    const int lane = tid & 63, w = tid >> 6;

    __shared__ float RhS[64][33];
    __shared__ float RwS[64][33];
    __shared__ unsigned short Pl[4][16][72];      // per-wave P^T tile
    {
        int q = tid & 63, seg = tid >> 6;
        int i = i0 + q, y1 = i >> 5, x1 = i & 31;
        const float* rh = Rh + (size_t)b * 64512 + (x1 * 32 + y1) * 63 + 31 - y1 + seg * 8;
        const float* rw = Rw + (size_t)b * 64512 + i * 63 + 31 - x1 + seg * 8;
        #pragma unroll
        for (int j = 0; j < 8; ++j) {
            RhS[q][seg * 8 + j] = rh[j];
            RwS[q][seg * 8 + j] = rw[j];
        }
    }
    __syncthreads();

    const int ql = lane & 15, g = lane >> 4;
    const int qw = i0 + w * 16;

    bf16x8 qf = *(const bf16x8*)&Qb[((size_t)bn * 1024 + qw + ql) * 32 + g * 8];
    const unsigned short* kp = Kb + ((size_t)bn * 1024 + ql) * 32 + g * 8;
    const unsigned short* vp = VtF + (size_t)bn * 32 * 512 + lane * 8;

    const float* rhrow = &RhS[w * 16 + ql][0];
    float rwA[4], rwB[4];
    #pragma unroll
    for (int r = 0; r < 4; ++r) {
        rwA[r] = RwS[w * 16 + ql][4 * g + r];
        rwB[r] = RwS[w * 16 + ql][16 + 4 * g + r];
    }

    f32x4 oaccT = {};                              // O^T rows g*4+r (row 8 = lsum)

    bf16x8 c0 = *(const bf16x8*)&kp[0 * 512];
    bf16x8 c1 = *(const bf16x8*)&kp[1 * 512];
    bf16x8 c2 = *(const bf16x8*)&kp[2 * 512];
    bf16x8 c3 = *(const bf16x8*)&kp[3 * 512];

    #pragma unroll 2
    for (int kt = 0; kt < 16; ++kt) {
        __builtin_amdgcn_s_setprio(1);
        f32x4 s0 = {}, s1 = {}, s2 = {}, s3 = {};
        s0 = __builtin_amdgcn_mfma_f32_16x16x32_bf16(c0, qf, s0, 0, 0, 0);
        s1 = __builtin_amdgcn_mfma_f32_16x16x32_bf16(c1, qf, s1, 0, 0, 0);
        s2 = __builtin_amdgcn_mfma_f32_16x16x32_bf16(c2, qf, s2, 0, 0, 0);
        s3 = __builtin_amdgcn_mfma_f32_16x16x32_bf16(c3, qf, s3, 0, 0, 0);
        __builtin_amdgcn_s_setprio(0);

        if (kt < 15) {                             // prefetch next K tile
            kp += 2048;
            c0 = *(const bf16x8*)&kp[0 * 512];
            c1 = *(const bf16x8*)&kp[1 * 512];
            c2 = *(const bf16x8*)&kp[2 * 512];
            c3 = *(const bf16x8*)&kp[3 * 512];
        }

        float rh0 = rhrow[2 * kt];
        float rh1 = rhrow[2 * kt + 1];

        // P = exp2(logit) directly (fixed max = 0) -> bf16 -> per-wave LDS
        float p00 = exp2f(s0[0] + rh0 + rwA[0]), p01 = exp2f(s0[1] + rh0 + rwA[1]);
        float p02 = exp2f(s0[2] + rh0 + rwA[2]), p03 = exp2f(s0[3] + rh0 + rwA[3]);
        float p10 = exp2f(s1[0] + rh0 + rwB[0]), p11 = exp2f(s1[1] + rh0 + rwB[1]);
        float p12 = exp2f(s1[2] + rh0 + rwB[2]), p13 = exp2f(s1[3] + rh0 + rwB[3]);
        float p20 = exp2f(s2[0] + rh1 + rwA[0]), p21 = exp2f(s2[1] + rh1 + rwA[1]);
        float p22 = exp2f(s2[2] + rh1 + rwA[2]), p23 = exp2f(s2[3] + rh1 + rwA[3]);
        float p30 = exp2f(s3[0] + rh1 + rwB[0]), p31 = exp2f(s3[1] + rh1 + rwB[1]);
        float p32 = exp2f(s3[2] + rh1 + rwB[2]), p33 = exp2f(s3[3] + rh1 + rwB[3]);

        const int key = 4 * g;
        *(unsigned*)&Pl[w][ql][key]      = cvt_pk_bf16(p00, p01);
        *(unsigned*)&Pl[w][ql][key + 2]  = cvt_pk_bf16(p02, p03);
        *(unsigned*)&Pl[w][ql][key + 16] = cvt_pk_bf16(p10, p11);
        *(unsigned*)&Pl[w][ql][key + 18] = cvt_pk_bf16(p12, p13);
        *(unsigned*)&Pl[w][ql][key + 32] = cvt_pk_bf16(p20, p21);
        *(unsigned*)&Pl[w][ql][key + 34] = cvt_pk_bf16(p22, p23);
        *(unsigned*)&Pl[w][ql][key + 48] = cvt_pk_bf16(p30, p31);
        *(unsigned*)&Pl[w][ql][key + 50] = cvt_pk_bf16(p32, p33);

        // O^T += V^T(keys) @ P^T  (VtF fragment-order: contiguous 1KB per frag)
        #pragma unroll
        for (int half = 0; half < 2; ++half) {
            bf16x8 vfr = *(const bf16x8*)&vp[(size_t)(kt * 2 + half) * 512];
            bf16x8 pfr = *(const bf16x8*)&Pl[w][ql][half * 32 + g * 8];
            __builtin_amdgcn_s_setprio(1);
            oaccT = __builtin_amdgcn_mfma_f32_16x16x32_bf16(vfr, pfr, oaccT, 0, 0, 0);
            __builtin_amdgcn_s_setprio(0);
        }
    }

    float lsum = __shfl(oaccT[0], 32 + ql, 64);    // row 8 lives in lane g=2, reg 0
    float inv = 1.0f / lsum;
    if (g < 2) {
        float4 o = {oaccT[0] * inv, oaccT[1] * inv, oaccT[2] * inv, oaccT[3] * inv};
        *(float4*)&attnout[((size_t)bn * 1024 + qw + ql) * 8 + g * 4] = o;
    }
}

// ---- attn 1x1 conv as MFMA: out[192+oc][s] = W[oc][c] @ attn_flat[c][s] per b ----
// B-frag: channel c lives at FLAT offset c*1024+s of the attn buffer (reference
// reshape is a flat reinterpretation) -> 8 stride-1024 f32 loads per lane.
__global__ __launch_bounds__(256) void attn_out_mfma_kernel(
    const unsigned short* __restrict__ Wa, const float* __restrict__ attn,
    const float* __restrict__ bias, float* __restrict__ out)
{
    const int b = blockIdx.y;
    const int tid = threadIdx.x;
    const int w = tid >> 6, lane = tid & 63;
    const int sg = blockIdx.x * 4 + w;            // 16-sp group, 0..63
    const int kc = lane >> 4, ln = lane & 15;
    const int s = sg * 16 + ln;

    const float* ab = attn + (size_t)b * 65536 + s;

    f32x4 acc0 = {}, acc1 = {}, acc2 = {}, acc3 = {};
    #pragma unroll
    for (int kchunk = 0; kchunk < 2; ++kchunk) {
        const int c0 = kchunk * 32 + kc * 8;
        const float* cp = ab + (size_t)c0 * 1024;
        bf16x8 bf;
        #pragma unroll
        for (int j = 0; j < 8; j += 2) {
            unsigned u = cvt_pk_bf16(cp[(size_t)j * 1024], cp[(size_t)(j + 1) * 1024]);
            bf[j]     = (short)u;
            bf[j + 1] = (short)(u >> 16);
        }

        const unsigned short* wp = Wa + (size_t)kchunk * 2048;
        bf16x8 a0 = *(const bf16x8*)&wp[(size_t)(0 * 64 + lane) * 8];
        bf16x8 a1 = *(const bf16x8*)&wp[(size_t)(1 * 64 + lane) * 8];
        bf16x8 a2 = *(const bf16x8*)&wp[(size_t)(2 * 64 + lane) * 8];
        bf16x8 a3 = *(const bf16x8*)&wp[(size_t)(3 * 64 + lane) * 8];
        acc0 = __builtin_amdgcn_mfma_f32_16x16x32_bf16(a0, bf, acc0, 0, 0, 0);
        acc1 = __builtin_amdgcn_mfma_f32_16x16x32_bf16(a1, bf, acc1, 0, 0, 0);
        acc2 = __builtin_amdgcn_mfma_f32_16x16x32_bf16(a2, bf, acc2, 0, 0, 0);
        acc3 = __builtin_amdgcn_mfma_f32_16x16x32_bf16(a3, bf, acc3, 0, 0, 0);
    }

    float* ob = out + ((size_t)b * 256 + 192) * 1024 + s;
    #pragma unroll
    for (int r = 0; r < 4; ++r) {
        int oc0 = 0 * 16 + kc * 4 + r;
        int oc1 = 1 * 16 + kc * 4 + r;
        int oc2 = 2 * 16 + kc * 4 + r;
        int oc3 = 3 * 16 + kc * 4 + r;
        ob[(size_t)oc0 * 1024] = acc0[r] + bias[oc0];
        ob[(size_t)oc1 * 1024] = acc1[r] + bias[oc1];
        ob[(size_t)oc2 * 1024] = acc2[r] + bias[oc2];
        ob[(size_t)oc3 * 1024] = acc3[r] + bias[oc3];
    }
}

extern "C" void kernel_launch(void* const* d_in, const int* in_sizes, int n_in,
                              void* d_out, int out_size, void* d_ws, size_t ws_size,
                              hipStream_t stream)
{
    const float* x          = (const float*)d_in[0];
    const float* kqv_w      = (const float*)d_in[1];
    const float* kqv_b      = (const float*)d_in[2];
    const float* conv_out_w = (const float*)d_in[3];
    const float* conv_out_b = (const float*)d_in[4];
    const float* attn_w     = (const float*)d_in[5];
    const float* attn_b     = (const float*)d_in[6];
    const float* rel_h      = (const float*)d_in[7];
    const float* rel_w      = (const float*)d_in[8];
    float* out = (float*)d_out;
    float* ws  = (float*)d_ws;

    // Disjoint layout (f32 offsets); ~32 MB total.
    float* ws_qf32 = ws;                                   // 1,310,720
    float* ws_rw   = ws + 1310720;                         //   516,096
    float* ws_rh   = ws + 1826816;                         //   516,096
    float* ws_attn = ws + 2342912;                         //   524,288
    unsigned short* Qb  = (unsigned short*)(ws + 2867200); // 2,097,152 u16
    unsigned short* Kb  = (unsigned short*)(ws + 3915776); // 2,097,152 u16
    unsigned short* VtF = (unsigned short*)(ws + 4964352); // 1,048,576 u16
    unsigned short* Xt2 = (unsigned short*)(ws + 5488640); // 2,367,488 u16
    unsigned short* Xq  = (unsigned short*)(ws + 6672384); // 2,097,152 u16
    unsigned short* Wp  = (unsigned short*)(ws + 7720960); //   442,368 u16
    unsigned short* Wq  = (unsigned short*)(ws + 7942144); //    98,304 u16
    unsigned short* Wa  = (unsigned short*)(ws + 7991296); //     4,096 u16

    pack_inputs_kernel<<<3214, 256, 0, stream>>>(
        x, conv_out_w, kqv_w, attn_w, Xt2, Xq, Wp, Wq, Kb, Qb, VtF, Wa);
    mfma_gemms_kernel<<<dim3(16, 9, 8), 256, 0, stream>>>(
        Wp, Wq, Xt2, Xq, conv_out_b, kqv_b, out, ws_qf32, Kb, Qb, VtF);
    rel_kernel<<<512, 256, 0, stream>>>(ws_qf32, rel_h, rel_w, ws_rh, ws_rw);
    attn_mfma_kernel<<<dim3(16, 64), 256, 0, stream>>>(
        Qb, Kb, VtF, ws_rh, ws_rw, ws_attn);
    attn_out_mfma_kernel<<<dim3(16, 8), 256, 0, stream>>>(
        Wa, ws_attn, attn_b, out);
}